// Round 1
// baseline (324.162 us; speedup 1.0000x reference)
//
#include <hip/hip_runtime.h>
#include <hip/hip_bf16.h>
#include <cstdint>
#include <cstddef>

#define DEV static __device__ __forceinline__

typedef float f32x4 __attribute__((ext_vector_type(4)));
typedef __bf16 bf16x8 __attribute__((ext_vector_type(8)));
typedef unsigned int u32x4 __attribute__((ext_vector_type(4)));
typedef unsigned short us4v __attribute__((ext_vector_type(4)));

static constexpr int BATCH  = 4;
static constexpr int SEQ    = 4096;
static constexpr int DMODEL = 1024;
static constexpr int DHEAD  = 64;

// ws layout (bytes):
//   WT  bf16 [3][64][1024]            @ 0        (393216)
//   Q   bf16 [B][S][64] (pre-scaled)  @ 393216   (2097152)
//   K   bf16 [B][S][64]               @ 2490368  (2097152)
//   VT  bf16 [B][64][S]               @ 4587520  (2097152)
static constexpr size_t WT_OFF = 0;
static constexpr size_t Q_OFF  = 393216;
static constexpr size_t K_OFF  = Q_OFF + 2097152;
static constexpr size_t VT_OFF = K_OFF + 2097152;

DEV unsigned short f2bf_bits(float f) {
    union { float f; unsigned u; } v; v.f = f;
    unsigned r = (v.u + 0x7fffu + ((v.u >> 16) & 1u)) >> 16;
    return (unsigned short)r;
}
DEV __bf16 f2bf(float f) {
    union { unsigned short s; __bf16 b; } o; o.s = f2bf_bits(f); return o.b;
}
DEV bf16x8 load_bf16x8(const unsigned short* p) {
    union { u32x4 u; bf16x8 b; } t;
    t.u = *(const u32x4*)p;
    return t.b;
}

// ---------------- kernel 0: W fp32 -> WT bf16 [3][64][1024] ----------------
__global__ __launch_bounds__(256) void wtrans_kernel(
        const float* __restrict__ Wq, const float* __restrict__ Wk,
        const float* __restrict__ Wv, unsigned short* __restrict__ WT) {
    int idx = blockIdx.x * 256 + threadIdx.x;     // 3*64*1024 = 196608 total
    int m = idx >> 16;
    int r = idx & 65535;
    int d = r >> 10, k = r & 1023;
    const float* W = (m == 0) ? Wq : ((m == 1) ? Wk : Wv);
    WT[idx] = f2bf_bits(W[k * DHEAD + d]);
}

// ---------------- kernel 1: fused QKV projection ----------------
// grid 256 x 256 threads; block = 64 rows, wave = 16 rows.
__global__ __launch_bounds__(256) void proj_kernel(
        const float* __restrict__ x, const unsigned short* __restrict__ WT,
        unsigned short* __restrict__ Qs, unsigned short* __restrict__ Kd,
        unsigned short* __restrict__ VT) {
    const int wave = threadIdx.x >> 6;
    const int lane = threadIdx.x & 63;
    const int lr = lane & 15, lg = lane >> 4;
    const int rowbase = blockIdx.x * 64 + wave * 16;

    const float* xrow = x + (size_t)(rowbase + lr) * DMODEL;

    f32x4 acc[3][4];
#pragma unroll
    for (int m = 0; m < 3; ++m)
#pragma unroll
        for (int t = 0; t < 4; ++t) acc[m][t] = (f32x4){0.f, 0.f, 0.f, 0.f};

    for (int k0 = 0; k0 < DMODEL; k0 += 32) {
        const float* ap = xrow + k0 + lg * 8;
        f32x4 a0 = *(const f32x4*)ap;
        f32x4 a1 = *(const f32x4*)(ap + 4);
        bf16x8 af;
        af[0] = f2bf(a0[0]); af[1] = f2bf(a0[1]); af[2] = f2bf(a0[2]); af[3] = f2bf(a0[3]);
        af[4] = f2bf(a1[0]); af[5] = f2bf(a1[1]); af[6] = f2bf(a1[2]); af[7] = f2bf(a1[3]);
#pragma unroll
        for (int m = 0; m < 3; ++m) {
#pragma unroll
            for (int t = 0; t < 4; ++t) {
                bf16x8 bf = load_bf16x8(WT + (size_t)(m * 64 + t * 16 + lr) * DMODEL + k0 + lg * 8);
                acc[m][t] = __builtin_amdgcn_mfma_f32_16x16x32_bf16(af, bf, acc[m][t], 0, 0, 0);
            }
        }
    }

    // fold 1/sqrt(64) * log2(e) into Q so attention softmax can use exp2
    const float QSCALE = 0.18033688011112042f;
    const int b = rowbase >> 12;          // / 4096
    const int srow = rowbase & 4095;
#pragma unroll
    for (int t = 0; t < 4; ++t) {
        us4v vv;
#pragma unroll
        for (int e = 0; e < 4; ++e) {
            int r = rowbase + lg * 4 + e;
            int d = t * 16 + lr;
            Qs[(size_t)r * DHEAD + d] = f2bf_bits(acc[0][t][e] * QSCALE);
            Kd[(size_t)r * DHEAD + d] = f2bf_bits(acc[1][t][e]);
            vv[e] = f2bf_bits(acc[2][t][e]);
        }
        // VT[b][d][srow + lg*4 .. +4): contiguous 8B store
        *(us4v*)(VT + ((size_t)b * DHEAD + t * 16 + lr) * SEQ + srow + lg * 4) = vv;
    }
}

// ---------------- kernel 2: causal flash attention ----------------
// grid 512 x 128 threads (2 waves). Each wave: 16 q-rows.
// Longest q-groups dispatched first for load balance.
__global__ __launch_bounds__(128) void attn_kernel(
        const unsigned short* __restrict__ Qs, const unsigned short* __restrict__ Kd,
        const unsigned short* __restrict__ VT, float* __restrict__ out) {
    __shared__ unsigned short plds[2][16 * 40];   // per-wave P buffer, rows padded to 40
    const int wave = threadIdx.x >> 6;
    const int lane = threadIdx.x & 63;
    const int lr = lane & 15, lg = lane >> 4;

    const int b  = blockIdx.x & 3;
    const int jb = blockIdx.x >> 2;               // 0..127
    const int gidx = 255 - (jb * 2 + wave);       // q-group (16 rows), longest first
    const int qbase = gidx * 16;

    const unsigned short* Qb = Qs + (size_t)b * SEQ * DHEAD;
    const unsigned short* Kb = Kd + (size_t)b * SEQ * DHEAD;
    const unsigned short* Vb = VT + (size_t)b * DHEAD * SEQ;

    bf16x8 qf0 = load_bf16x8(Qb + (size_t)(qbase + lr) * DHEAD + lg * 8);
    bf16x8 qf1 = load_bf16x8(Qb + (size_t)(qbase + lr) * DHEAD + 32 + lg * 8);

    f32x4 o[4];
#pragma unroll
    for (int t = 0; t < 4; ++t) o[t] = (f32x4){0.f, 0.f, 0.f, 0.f};
    float m[4], l[4];
#pragma unroll
    for (int e = 0; e < 4; ++e) { m[e] = -1e30f; l[e] = 0.f; }

    unsigned short* pw = plds[wave];
    const int kv_end = qbase + 16;
    for (int kv0 = 0; kv0 < kv_end; kv0 += 32) {
        bf16x8 kf[2][2], vf[4];
#pragma unroll
        for (int f = 0; f < 2; ++f)
#pragma unroll
            for (int h = 0; h < 2; ++h)
                kf[f][h] = load_bf16x8(Kb + (size_t)(kv0 + f * 16 + lr) * DHEAD + h * 32 + lg * 8);
#pragma unroll
        for (int t = 0; t < 4; ++t)
            vf[t] = load_bf16x8(Vb + (size_t)(t * 16 + lr) * SEQ + kv0 + lg * 8);

        f32x4 sf[2];
#pragma unroll
        for (int f = 0; f < 2; ++f) {
            f32x4 z = (f32x4){0.f, 0.f, 0.f, 0.f};
            z = __builtin_amdgcn_mfma_f32_16x16x32_bf16(qf0, kf[f][0], z, 0, 0, 0);
            z = __builtin_amdgcn_mfma_f32_16x16x32_bf16(qf1, kf[f][1], z, 0, 0, 0);
            sf[f] = z;
        }

        if (kv0 + 31 > qbase) {   // causal mask needed on this step
#pragma unroll
            for (int f = 0; f < 2; ++f) {
                int kabs = kv0 + f * 16 + lr;
#pragma unroll
                for (int e = 0; e < 4; ++e) {
                    int qabs = qbase + lg * 4 + e;
                    if (kabs > qabs) sf[f][e] = -1e30f;
                }
            }
        }

        // row max over this 32-key block (rows live in 16-lane groups)
        float mb[4];
#pragma unroll
        for (int e = 0; e < 4; ++e) mb[e] = fmaxf(sf[0][e], sf[1][e]);
#pragma unroll
        for (int d = 1; d < 16; d <<= 1)
#pragma unroll
            for (int e = 0; e < 4; ++e) mb[e] = fmaxf(mb[e], __shfl_xor(mb[e], d));

        float sc[4];
#pragma unroll
        for (int e = 0; e < 4; ++e) {
            float mn = fmaxf(m[e], mb[e]);
            sc[e] = exp2f(m[e] - mn);
            m[e] = mn;
        }
#pragma unroll
        for (int f = 0; f < 2; ++f)
#pragma unroll
            for (int e = 0; e < 4; ++e)
                sf[f][e] = exp2f(sf[f][e] - m[e]);

        float sb[4];
#pragma unroll
        for (int e = 0; e < 4; ++e) sb[e] = sf[0][e] + sf[1][e];
#pragma unroll
        for (int d = 1; d < 16; d <<= 1)
#pragma unroll
            for (int e = 0; e < 4; ++e) sb[e] += __shfl_xor(sb[e], d);

#pragma unroll
        for (int e = 0; e < 4; ++e) l[e] = l[e] * sc[e] + sb[e];
#pragma unroll
        for (int t = 0; t < 4; ++t)
#pragma unroll
            for (int e = 0; e < 4; ++e) o[t][e] *= sc[e];

        // transpose P (acc layout -> A-frag layout) through wave-local LDS
#pragma unroll
        for (int f = 0; f < 2; ++f)
#pragma unroll
            for (int e = 0; e < 4; ++e)
                pw[(lg * 4 + e) * 40 + f * 16 + lr] = f2bf_bits(sf[f][e]);
        asm volatile("s_waitcnt lgkmcnt(0)" ::: "memory");
        __builtin_amdgcn_sched_barrier(0);
        bf16x8 pa = load_bf16x8(pw + lr * 40 + lg * 8);

#pragma unroll
        for (int t = 0; t < 4; ++t)
            o[t] = __builtin_amdgcn_mfma_f32_16x16x32_bf16(pa, vf[t], o[t], 0, 0, 0);
    }

    float* ob = out + (size_t)b * SEQ * DHEAD;
#pragma unroll
    for (int e = 0; e < 4; ++e) {
        float inv = 1.0f / l[e];
        int r = qbase + lg * 4 + e;
#pragma unroll
        for (int t = 0; t < 4; ++t)
            ob[(size_t)r * DHEAD + t * 16 + lr] = o[t][e] * inv;
    }
}

extern "C" void kernel_launch(void* const* d_in, const int* in_sizes, int n_in,
                              void* d_out, int out_size, void* d_ws, size_t ws_size,
                              hipStream_t stream) {
    const float* x  = (const float*)d_in[0];
    const float* Wq = (const float*)d_in[1];
    const float* Wk = (const float*)d_in[2];
    const float* Wv = (const float*)d_in[3];
    float* out = (float*)d_out;

    char* ws = (char*)d_ws;
    unsigned short* WT = (unsigned short*)(ws + WT_OFF);
    unsigned short* Q  = (unsigned short*)(ws + Q_OFF);
    unsigned short* K  = (unsigned short*)(ws + K_OFF);
    unsigned short* VT = (unsigned short*)(ws + VT_OFF);

    hipLaunchKernelGGL(wtrans_kernel, dim3(768), dim3(256), 0, stream, Wq, Wk, Wv, WT);
    hipLaunchKernelGGL(proj_kernel,   dim3(256), dim3(256), 0, stream, x, WT, Q, K, VT);
    hipLaunchKernelGGL(attn_kernel,   dim3(512), dim3(128), 0, stream, Q, K, VT, out);
}

// Round 2
// 217.260 us; speedup vs baseline: 1.4920x; 1.4920x over previous
//
#include <hip/hip_runtime.h>
#include <hip/hip_bf16.h>
#include <cstdint>
#include <cstddef>

#define DEV static __device__ __forceinline__

typedef float f32x4 __attribute__((ext_vector_type(4)));
typedef __bf16 bf16x8 __attribute__((ext_vector_type(8)));
typedef unsigned int u32x4 __attribute__((ext_vector_type(4)));
typedef unsigned short us4v __attribute__((ext_vector_type(4)));

static constexpr int BATCH  = 4;
static constexpr int SEQ    = 4096;
static constexpr int DMODEL = 1024;
static constexpr int DHEAD  = 64;

// ws layout (bytes):
//   WT  bf16 [3][64][1024]            @ 0        (393216)
//   Q   bf16 [B][S][64] (pre-scaled)  @ 393216   (2097152)
//   K   bf16 [B][S][64]               @ 2490368  (2097152)
//   VT  bf16 [B][64][S]               @ 4587520  (2097152)
static constexpr size_t WT_OFF = 0;
static constexpr size_t Q_OFF  = 393216;
static constexpr size_t K_OFF  = Q_OFF + 2097152;
static constexpr size_t VT_OFF = K_OFF + 2097152;

DEV unsigned short f2bf_bits(float f) {
    union { float f; unsigned u; } v; v.f = f;
    unsigned r = (v.u + 0x7fffu + ((v.u >> 16) & 1u)) >> 16;
    return (unsigned short)r;
}
DEV __bf16 f2bf(float f) {
    union { unsigned short s; __bf16 b; } o; o.s = f2bf_bits(f); return o.b;
}
DEV bf16x8 load_bf16x8(const unsigned short* p) {
    union { u32x4 u; bf16x8 b; } t;
    t.u = *(const u32x4*)p;
    return t.b;
}
DEV unsigned cvt_pk_bf16(float lo, float hi) {
    unsigned r;
    asm("v_cvt_pk_bf16_f32 %0, %1, %2" : "=v"(r) : "v"(lo), "v"(hi));
    return r;
}

// ---------------- kernel 0: W fp32 -> WT bf16 [3][64][1024] ----------------
__global__ __launch_bounds__(256) void wtrans_kernel(
        const float* __restrict__ Wq, const float* __restrict__ Wk,
        const float* __restrict__ Wv, unsigned short* __restrict__ WT) {
    int idx = blockIdx.x * 256 + threadIdx.x;     // 3*64*1024 = 196608 total
    int m = idx >> 16;
    int r = idx & 65535;
    int d = r >> 10, k = r & 1023;
    const float* W = (m == 0) ? Wq : ((m == 1) ? Wk : Wv);
    WT[idx] = f2bf_bits(W[k * DHEAD + d]);
}

// ---------------- kernel 1: fused QKV projection, split-K x2 ----------------
// grid 512 x 256 threads. Block: 2 row-tiles (16 rows) x 2 K-halves.
__global__ __launch_bounds__(256, 2) void proj_kernel(
        const float* __restrict__ x, const unsigned short* __restrict__ WT,
        unsigned short* __restrict__ Qs, unsigned short* __restrict__ Kd,
        unsigned short* __restrict__ VT) {
    __shared__ float plds[2 * 12 * 256];          // 24 KiB partials
    const int wave = threadIdx.x >> 6;
    const int lane = threadIdx.x & 63;
    const int lr = lane & 15, lg = lane >> 4;
    const int mt = wave & 1, kh = wave >> 1;
    const int rowbase = blockIdx.x * 32 + mt * 16;

    const float* xrow = x + (size_t)(rowbase + lr) * DMODEL + kh * 512;
    const unsigned short* WTh = WT + kh * 512;

    f32x4 acc[3][4];
#pragma unroll
    for (int m = 0; m < 3; ++m)
#pragma unroll
        for (int t = 0; t < 4; ++t) acc[m][t] = (f32x4){0.f, 0.f, 0.f, 0.f};

    for (int k0 = 0; k0 < 512; k0 += 32) {
        const float* ap = xrow + k0 + lg * 8;
        f32x4 a0 = *(const f32x4*)ap;
        f32x4 a1 = *(const f32x4*)(ap + 4);
        bf16x8 af;
        af[0] = f2bf(a0[0]); af[1] = f2bf(a0[1]); af[2] = f2bf(a0[2]); af[3] = f2bf(a0[3]);
        af[4] = f2bf(a1[0]); af[5] = f2bf(a1[1]); af[6] = f2bf(a1[2]); af[7] = f2bf(a1[3]);
#pragma unroll
        for (int m = 0; m < 3; ++m) {
#pragma unroll
            for (int t = 0; t < 4; ++t) {
                bf16x8 bf = load_bf16x8(WTh + (size_t)(m * 64 + t * 16 + lr) * DMODEL + k0 + lg * 8);
                acc[m][t] = __builtin_amdgcn_mfma_f32_16x16x32_bf16(af, bf, acc[m][t], 0, 0, 0);
            }
        }
    }

    float* pl = plds + mt * (12 * 256);
    if (kh == 1) {
#pragma unroll
        for (int m = 0; m < 3; ++m)
#pragma unroll
            for (int t = 0; t < 4; ++t)
                *(f32x4*)(pl + ((m * 4 + t) * 64 + lane) * 4) = acc[m][t];
    }
    __syncthreads();
    if (kh == 0) {
#pragma unroll
        for (int m = 0; m < 3; ++m)
#pragma unroll
            for (int t = 0; t < 4; ++t)
                acc[m][t] += *(const f32x4*)(pl + ((m * 4 + t) * 64 + lane) * 4);

        // fold 1/sqrt(64) * log2(e) into Q so attention softmax can use exp2
        const float QSCALE = 0.18033688011112042f;
        const int b = rowbase >> 12;
        const int srow = rowbase & 4095;
#pragma unroll
        for (int t = 0; t < 4; ++t) {
            us4v vv;
#pragma unroll
            for (int e = 0; e < 4; ++e) {
                int r = rowbase + lg * 4 + e;
                int d = t * 16 + lr;
                Qs[(size_t)r * DHEAD + d] = f2bf_bits(acc[0][t][e] * QSCALE);
                Kd[(size_t)r * DHEAD + d] = f2bf_bits(acc[1][t][e]);
                vv[e] = f2bf_bits(acc[2][t][e]);
            }
            *(us4v*)(VT + ((size_t)b * DHEAD + t * 16 + lr) * SEQ + srow + lg * 4) = vv;
        }
    }
}

// ---------------- kernel 2: causal flash attention ----------------
// grid 1024 x 128 threads (2 waves). Block = one 16-row q-group; the two
// waves split the KV range (even/odd 64-key blocks) and merge via LDS.
// Swapped QK^T: lane holds a full P-row (q = lane&15), m/l are scalars.
__global__ __launch_bounds__(128, 2) void attn_kernel(
        const unsigned short* __restrict__ Qs, const unsigned short* __restrict__ Kd,
        const unsigned short* __restrict__ VT, float* __restrict__ out) {
    __shared__ unsigned short plds[2][16 * 88];   // per-wave P buffer, stride 88 bf16
    __shared__ float olds[16 * 68];               // wave1 O partial
    __shared__ float mlds[16], llds[16];

    const int wave = threadIdx.x >> 6;
    const int lane = threadIdx.x & 63;
    const int lr = lane & 15, lg = lane >> 4;

    const int b = blockIdx.x & 3;
    const int g = 255 - (blockIdx.x >> 2);        // longest q-groups first
    const int qbase = g * 16;
    const int qabs = qbase + lr;

    const unsigned short* Qb = Qs + (size_t)b * SEQ * DHEAD;
    const unsigned short* Kb = Kd + (size_t)b * SEQ * DHEAD;
    const unsigned short* Vb = VT + (size_t)b * DHEAD * SEQ;

    const bf16x8 qf0 = load_bf16x8(Qb + (size_t)qabs * DHEAD + lg * 8);
    const bf16x8 qf1 = load_bf16x8(Qb + (size_t)qabs * DHEAD + 32 + lg * 8);

    f32x4 o[4];
#pragma unroll
    for (int t = 0; t < 4; ++t) o[t] = (f32x4){0.f, 0.f, 0.f, 0.f};
    float m = -1e30f, l = 0.f;

    unsigned* pwd = (unsigned*)plds[wave];
    const unsigned short* prd = plds[wave];

    const int nblk = (qbase + 16 + 63) >> 6;      // 64-key blocks covering [0, qbase+16)
    for (int j = wave; j < nblk; j += 2) {
        const int kv0 = j << 6;

        bf16x8 kf[4][2];
#pragma unroll
        for (int kb = 0; kb < 4; ++kb)
#pragma unroll
            for (int h = 0; h < 2; ++h)
                kf[kb][h] = load_bf16x8(Kb + (size_t)(kv0 + kb * 16 + lr) * DHEAD + h * 32 + lg * 8);
        bf16x8 vf[2][4];
#pragma unroll
        for (int c = 0; c < 2; ++c)
#pragma unroll
            for (int t = 0; t < 4; ++t)
                vf[c][t] = load_bf16x8(Vb + (size_t)(t * 16 + lr) * SEQ + kv0 + c * 32 + lg * 8);

        // S^T = K . Q^T : lane (lr,lg) holds S[k=kv0+16kb+4lg+e][q=qbase+lr]
        f32x4 sf[4];
#pragma unroll
        for (int kb = 0; kb < 4; ++kb) {
            f32x4 z = (f32x4){0.f, 0.f, 0.f, 0.f};
            z = __builtin_amdgcn_mfma_f32_16x16x32_bf16(kf[kb][0], qf0, z, 0, 0, 0);
            z = __builtin_amdgcn_mfma_f32_16x16x32_bf16(kf[kb][1], qf1, z, 0, 0, 0);
            sf[kb] = z;
        }

        if (kv0 + 63 > qbase) {                   // causal mask (wave-uniform branch)
#pragma unroll
            for (int kb = 0; kb < 4; ++kb)
#pragma unroll
                for (int e = 0; e < 4; ++e) {
                    int kabs = kv0 + kb * 16 + lg * 4 + e;
                    if (kabs > qabs) sf[kb][e] = -1e30f;
                }
        }

        // row max: 15 in-lane + 2 shfl (lanes {lr, lr+16, lr+32, lr+48})
        float mb;
#pragma unroll
        for (int kb = 0; kb < 4; ++kb) {
            float t0 = fmaxf(fmaxf(sf[kb][0], sf[kb][1]), fmaxf(sf[kb][2], sf[kb][3]));
            mb = (kb == 0) ? t0 : fmaxf(mb, t0);
        }
        mb = fmaxf(mb, __shfl_xor(mb, 16));
        mb = fmaxf(mb, __shfl_xor(mb, 32));

        if (__any(mb > m)) {                      // defer-max: skip rescale if no growth
            float mn = fmaxf(m, mb);
            float sc = exp2f(m - mn);
            m = mn;
            l *= sc;
#pragma unroll
            for (int e = 0; e < 4; ++e) {
                float sce = __shfl(sc, (lane & 48) | (((lane >> 2) & 12) + e));
#pragma unroll
                for (int t = 0; t < 4; ++t) o[t][e] *= sce;
            }
        }

        float s = 0.f;
#pragma unroll
        for (int kb = 0; kb < 4; ++kb)
#pragma unroll
            for (int e = 0; e < 4; ++e) {
                float pv = exp2f(sf[kb][e] - m);
                sf[kb][e] = pv;
                s += pv;
            }
        s += __shfl_xor(s, 16);
        s += __shfl_xor(s, 32);
        l += s;

        // pack P to bf16 pairs, transpose through wave-local LDS
#pragma unroll
        for (int kb = 0; kb < 4; ++kb)
#pragma unroll
            for (int ps = 0; ps < 2; ++ps)
                pwd[lr * 44 + kb * 8 + lg * 2 + ps] =
                    cvt_pk_bf16(sf[kb][2 * ps], sf[kb][2 * ps + 1]);

        asm volatile("s_waitcnt lgkmcnt(0)" ::: "memory");
        __builtin_amdgcn_sched_barrier(0);

        bf16x8 pa0 = load_bf16x8(prd + lr * 88 + lg * 8);
        bf16x8 pa1 = load_bf16x8(prd + lr * 88 + 32 + lg * 8);
#pragma unroll
        for (int t = 0; t < 4; ++t) {
            o[t] = __builtin_amdgcn_mfma_f32_16x16x32_bf16(pa0, vf[0][t], o[t], 0, 0, 0);
            o[t] = __builtin_amdgcn_mfma_f32_16x16x32_bf16(pa1, vf[1][t], o[t], 0, 0, 0);
        }
    }

    // merge the two waves' partials (m, l, o)
    if (wave == 1) {
#pragma unroll
        for (int t = 0; t < 4; ++t)
#pragma unroll
            for (int e = 0; e < 4; ++e)
                olds[(lg * 4 + e) * 68 + t * 16 + lr] = o[t][e];
        if (lg == 0) { mlds[lr] = m; llds[lr] = l; }
    }
    __syncthreads();
    if (wave == 0) {
        float m1 = mlds[lr], l1 = llds[lr];
        float ms = fmaxf(m, m1);
        float a0 = exp2f(m - ms), a1 = exp2f(m1 - ms);
        float inv = 1.f / (l * a0 + l1 * a1);
        a0 *= inv; a1 *= inv;
        float* ob = out + ((size_t)b * SEQ + qbase) * DHEAD;
#pragma unroll
        for (int e = 0; e < 4; ++e) {
            int src = (lane & 48) | (((lane >> 2) & 12) + e);
            float A0 = __shfl(a0, src);
            float A1 = __shfl(a1, src);
#pragma unroll
            for (int t = 0; t < 4; ++t) {
                float o1 = olds[(lg * 4 + e) * 68 + t * 16 + lr];
                ob[(size_t)(lg * 4 + e) * DHEAD + t * 16 + lr] = o[t][e] * A0 + o1 * A1;
            }
        }
    }
}

extern "C" void kernel_launch(void* const* d_in, const int* in_sizes, int n_in,
                              void* d_out, int out_size, void* d_ws, size_t ws_size,
                              hipStream_t stream) {
    const float* x  = (const float*)d_in[0];
    const float* Wq = (const float*)d_in[1];
    const float* Wk = (const float*)d_in[2];
    const float* Wv = (const float*)d_in[3];
    float* out = (float*)d_out;

    char* ws = (char*)d_ws;
    unsigned short* WT = (unsigned short*)(ws + WT_OFF);
    unsigned short* Q  = (unsigned short*)(ws + Q_OFF);
    unsigned short* K  = (unsigned short*)(ws + K_OFF);
    unsigned short* VT = (unsigned short*)(ws + VT_OFF);

    hipLaunchKernelGGL(wtrans_kernel, dim3(768),  dim3(256), 0, stream, Wq, Wk, Wv, WT);
    hipLaunchKernelGGL(proj_kernel,   dim3(512),  dim3(256), 0, stream, x, WT, Q, K, VT);
    hipLaunchKernelGGL(attn_kernel,   dim3(1024), dim3(128), 0, stream, Q, K, VT, out);
}